// Round 6
// baseline (402.598 us; speedup 1.0000x reference)
//
#include <hip/hip_runtime.h>
#include <hip/hip_bf16.h>

typedef __attribute__((ext_vector_type(8))) short bf16x8;
typedef __attribute__((ext_vector_type(4))) float f32x4;
typedef __attribute__((ext_vector_type(4))) _Float16 f16x4;
typedef __attribute__((ext_vector_type(8))) _Float16 f16x8;
typedef __attribute__((ext_vector_type(4))) unsigned short u16x4;

#define B_ 2
#define S_ 2048
#define E_ 2048
#define H_ 16
#define D_ 128
#define ELEMS (B_*S_*E_)   // 8388608 elements of [B,S,2048]
#define WELEMS (E_*E_)     // 4194304 elements per weight matrix

__device__ __forceinline__ unsigned short f2bf(float x) {
  unsigned int u = __float_as_uint(x);
  u += 0x7fffu + ((u >> 16) & 1u);
  return (unsigned short)(u >> 16);
}

__device__ __forceinline__ void async_load16(const void* g, void* l) {
  __builtin_amdgcn_global_load_lds(
      (const __attribute__((address_space(1))) unsigned int*)g,
      (__attribute__((address_space(3))) unsigned int*)l, 16, 0, 0);
}

// f32 -> bf16 (RNE), vectorized x4. n4 = n/4.
__global__ __launch_bounds__(256)
void cvt_f32_bf16(const float* __restrict__ src, unsigned short* __restrict__ dst, int n4)
{
  const int i = blockIdx.x * 256 + threadIdx.x;
  if (i < n4) {
    const f32x4 v = ((const f32x4*)src)[i];
    u16x4 o;
    o.x = f2bf(v.x); o.y = f2bf(v.y); o.z = f2bf(v.z); o.w = f2bf(v.w);
    ((u16x4*)dst)[i] = o;
  }
}

// four equally-sized weight tensors in one launch (blockIdx.y selects)
__global__ __launch_bounds__(256)
void cvt4_f32_bf16(const float* __restrict__ s0, const float* __restrict__ s1,
                   const float* __restrict__ s2, const float* __restrict__ s3,
                   unsigned short* __restrict__ d0, unsigned short* __restrict__ d1,
                   unsigned short* __restrict__ d2, unsigned short* __restrict__ d3,
                   int n4)
{
  const int i = blockIdx.x * 256 + threadIdx.x;
  if (i >= n4) return;
  const float* s; unsigned short* d;
  switch (blockIdx.y) {
    case 0: s = s0; d = d0; break;
    case 1: s = s1; d = d1; break;
    case 2: s = s2; d = d2; break;
    default: s = s3; d = d3; break;
  }
  const f32x4 v = ((const f32x4*)s)[i];
  u16x4 o;
  o.x = f2bf(v.x); o.y = f2bf(v.y); o.z = f2bf(v.z); o.w = f2bf(v.w);
  ((u16x4*)d)[i] = o;
}

// ---------------------------------------------------------------------------
// 256x128-tile GEMM, ring-3 LDS pipeline (R5). Measured R4/R5: the 2-buffer
// schedule had ~2000 cyc/K-tile overhead (vmcnt gates waited on DMAs issued
// only ~1 phase earlier -> HBM latency exposed; 4 barriers/K-tile forced
// lockstep convoys). This version: 3 x 48KiB buffers (144 KiB), staging 2
// K-tiles ahead (each DMA gets ~2 K-tile times to land, vmcnt(6) is then a
// check not a stall), and ONE barrier pair per K-tile. Middle lgkmcnt has no
// barrier so waves desynchronize and ds_reads overlap other waves' MFMAs.
// 512 thr = 8 waves (4M x 2N), wave tile 64x64, BK=64 as two 32-k halves.
// Swizzle (verified 0 conflicts R4): 16B-slot ^= (row>>1)&3; DMA dest linear,
// inverse swizzle pre-applied on per-lane global source (both-sides rule).
// Grids stay exact rounds: QKV 768 = 3x256, Wo 256 = 1x256.
template<int OUTMODE>
__global__ __launch_bounds__(512, 2)
void gemm_ring3(const __hip_bfloat16* __restrict__ A,
                const __hip_bfloat16* __restrict__ Bw,
                void* __restrict__ C, int M, int N, int K)
{
  extern __shared__ char lds[];
  const int lane = threadIdx.x & 63;
  const int w    = threadIdx.x >> 6;   // 0..7
  const int fr   = lane & 15;
  const int fg   = lane >> 4;          // 0..3

  // XCD-aware swizzle of the linear block id (grid % 8 == 0)
  const int nblk = N >> 7;             // N / 128
  const int cpx  = gridDim.x >> 3;
  const int lin  = blockIdx.x;
  const int swz  = (lin & 7) * cpx + (lin >> 3);
  const int m0 = (swz / nblk) << 8;
  const int n0 = (swz % nblk) << 7;

  // LDS geometry (per 48-KB buffer): A at 0 (kk*16384), B at 32768 (kk*8192);
  // row stride 64 B; 16B-slot ^= (row>>1)&3.
  const int Ssw = (fg ^ ((fr >> 1) & 3)) << 4;
  const int pA  = ((w >> 1) * 64 + fr) * 64 + Ssw;          // + mi*1024 + kk*16384
  const int pB  = 32768 + ((w & 1) * 64 + fr) * 64 + Ssw;   // + nj*1024 + kk*8192

  // Staging: per kk-half, 3 x 8KB units (A rows 0-127, A rows 128-255, B rows
  // 0-127); each thread 1 DMA per unit. Dest slot linear in lane (valid for
  // global_load_lds); source k-group pre-swizzled (lane&3)^((lane>>3)&3).
  const int srow = w * 16 + (lane >> 2);               // 0..127
  const int ks   = ((lane & 3) ^ ((lane >> 3) & 3)) * 8;
  const __hip_bfloat16* Asrc = A  + (size_t)(m0 + srow) * K + ks;
  const __hip_bfloat16* Bsrc = Bw + (size_t)(n0 + srow) * K + ks;
  const int dstA = srow * 64 + (lane & 3) * 16;        // < 8192

#define STG(NB, KH, KT) do {                                                   \
    const size_t ko_ = (size_t)(KT)*64 + (KH)*32;                              \
    async_load16(Asrc + ko_,                                                   \
                 lds + (NB)*49152 + (KH)*16384 + dstA);                        \
    async_load16(Asrc + (size_t)128*K + ko_,                                   \
                 lds + (NB)*49152 + (KH)*16384 + 8192 + dstA);                 \
    async_load16(Bsrc + ko_,                                                   \
                 lds + (NB)*49152 + 32768 + (KH)*8192 + dstA);                 \
  } while (0)

#define RD(AR, BR, KK, BB) do {                                                \
    const char* pa_ = lds + (BB)*49152 + (KK)*16384 + pA;                      \
    AR[0] = *(const bf16x8*)(pa_);        AR[1] = *(const bf16x8*)(pa_ + 1024);\
    AR[2] = *(const bf16x8*)(pa_ + 2048); AR[3] = *(const bf16x8*)(pa_ + 3072);\
    const char* pb_ = lds + (BB)*49152 + (KK)*8192 + pB;                       \
    BR[0] = *(const bf16x8*)(pb_);        BR[1] = *(const bf16x8*)(pb_ + 1024);\
    BR[2] = *(const bf16x8*)(pb_ + 2048); BR[3] = *(const bf16x8*)(pb_ + 3072);\
  } while (0)

#define MFMA16(AR, BR)                                                         \
    _Pragma("unroll")                                                          \
    for (int i_ = 0; i_ < 4; i_++)                                             \
    _Pragma("unroll")                                                          \
    for (int j_ = 0; j_ < 4; j_++)                                             \
      acc[i_][j_] = __builtin_amdgcn_mfma_f32_16x16x32_bf16(                   \
          AR[i_], BR[j_], acc[i_][j_], 0, 0, 0)

#define BARX() __builtin_amdgcn_s_barrier()
#define LGKM0() do { asm volatile("s_waitcnt lgkmcnt(0)" ::: "memory");        \
                     __builtin_amdgcn_sched_barrier(0); } while (0)
#define VMW(NN) asm volatile("s_waitcnt vmcnt(" #NN ")" ::: "memory")
#define PRIO(P) __builtin_amdgcn_s_setprio(P)

  f32x4 acc[4][4];
#pragma unroll
  for (int i = 0; i < 4; i++)
#pragma unroll
    for (int j = 0; j < 4; j++) acc[i][j] = (f32x4)0.0f;

  bf16x8 a0[4], b0[4], a1[4], b1[4];

  // prologue: stage tile 0 -> buf0, tile 1 -> buf1 (6 DMAs each, per wave)
  STG(0, 0, 0);
  STG(0, 1, 0);
  STG(1, 0, 1);
  STG(1, 1, 1);
  VMW(6);          // tile 0's 6 landed; tile 1's 6 still in flight
  BARX();

  const int nk = K >> 6;   // K-tiles of 64
  int bb = 0;
  for (int t = 0; t < nk; ++t) {
    const int nb = (bb == 0) ? 2 : bb - 1;   // (bb+2)%3
    const bool stg = (t + 2) < nk;
    // kk = 0
    RD(a0, b0, 0, bb);
    if (stg) STG(nb, 0, t + 2);
    BARX(); LGKM0();
    PRIO(1); MFMA16(a0, b0); PRIO(0);
    // kk = 1 (no barrier: waves desync, LDS overlaps other waves' MFMA)
    RD(a1, b1, 1, bb);
    if (stg) STG(nb, 1, t + 2);
    LGKM0();
    PRIO(1); MFMA16(a1, b1); PRIO(0);
    // gate: tile t+1 (issued 1-2 iters ago) must be resident before next RD.
    // With stg: outstanding = t+1's 6 + t+2's 6 -> vmcnt(6) passes when t+1
    // done, leaves t+2 in flight. Tail: drain everything.
    if (stg) { VMW(6); } else { VMW(0); }
    BARX();
    bb = (bb == 2) ? 0 : bb + 1;
  }

  // epilogue: direct scattered C write (same fragment->C map as before)
  const int wr = (w >> 1) * 64, wc = (w & 1) * 64;
#pragma unroll
  for (int mi = 0; mi < 4; mi++) {
    const int row = m0 + wr + mi*16 + fg*4;
#pragma unroll
    for (int nj = 0; nj < 4; nj++) {
      const int col = n0 + wc + nj*16 + fr;
#pragma unroll
      for (int r = 0; r < 4; r++) {
        if (OUTMODE == 1) {
          ((float*)C)[(size_t)(row + r)*N + col] = acc[mi][nj][r];
        } else if (OUTMODE == 0) {
          ((unsigned short*)C)[(size_t)(row + r)*N + col] = f2bf(acc[mi][nj][r]);
        } else if (OUTMODE == 2) {
          const int rr = row + r;
          const int b = rr >> 11, s = rr & 2047;
          const int h = col >> 7, d = col & 127;
          ((unsigned short*)C)[(((size_t)(b*H_ + h) << 11) + s)*D_ + d] = f2bf(acc[mi][nj][r]);
        } else {   // OUTMODE == 3: fused QKV, outputs contiguous ELEMS apart
          const int rr = row + r;
          const int b = rr >> 11, s = rr & 2047;
          const int t2 = col >> 11;            // 0=Q 1=K 2=V
          const int h = (col >> 7) & 15, d = col & 127;
          ((unsigned short*)C)[(size_t)t2*ELEMS +
              (((size_t)(b*H_ + h) << 11) + s)*D_ + d] = f2bf(acc[mi][nj][r]);
        }
      }
    }
  }
#undef STG
#undef RD
#undef MFMA16
#undef BARX
#undef LGKM0
#undef VMW
#undef PRIO
}

// xpos rotary, in place on head-major bf16 Q and K [b,h,s,d].
__global__ __launch_bounds__(256)
void xpos_rotary(__hip_bfloat16* __restrict__ Q, __hip_bfloat16* __restrict__ Kt)
{
  const int idx = blockIdx.x * 256 + threadIdx.x;   // [0, B*H*S*64)
  const int j = idx & 63;
  const int s = (idx >> 6) & 2047;
  const float seq = (float)(s - 1024) * (1.0f/512.0f);
  const float dr = 2.0f + 2.0f*(float)j;
  const float theta = expf(dr * (1.0f/128.0f) * -9.210340371976184f);
  const float zeta  = (dr * (1.0f/64.0f) + 51.2f) * (1.0f/52.2f);
  const float ang = seq * theta;
  const float c  = cosf(ang);
  const float sn = sinf(ang);
  const float t  = expf(seq * logf(zeta));
  const float it = 1.0f / t;

  const size_t base = (size_t)(idx >> 6) * 128 + 2*j;
  unsigned short* Qs = (unsigned short*)Q;
  unsigned short* Ks = (unsigned short*)Kt;
  const float q0 = __bfloat162float(Q[base]),  q1 = __bfloat162float(Q[base+1]);
  Qs[base]   = f2bf((q0*c - q1*sn) * t);
  Qs[base+1] = f2bf((q1*c + q0*sn) * t);
  const float k0 = __bfloat162float(Kt[base]), k1 = __bfloat162float(Kt[base+1]);
  Ks[base]   = f2bf((k0*c - k1*sn) * it);
  Ks[base+1] = f2bf((k1*c + k0*sn) * it);
}

// Vh [b,h,s,d] bf16 -> VT3 packed f16:
// per (bh, kt=s/64) 16-KB tile, inner offset = d*64 + g*16 + half*8 + s1*4 + r
// where key=s%64 = (half*2+s1)*16 + g*4 + r.
__global__ __launch_bounds__(256)
void transpose_v(const __hip_bfloat16* __restrict__ Vh, _Float16* __restrict__ VT3)
{
  __shared__ float tile[32][33];
  const int tx = threadIdx.x, ty = threadIdx.y;      // block (32, 8)
  const int bh = blockIdx.z;
  const int s0 = blockIdx.x * 32, d0 = blockIdx.y * 32;
  const int kt = s0 >> 6, koff = s0 & 63;
#pragma unroll
  for (int r = 0; r < 4; r++) {
    const int s = s0 + ty + r*8;
    tile[ty + r*8][tx] = __bfloat162float(Vh[((size_t)bh*S_ + s)*D_ + d0 + tx]);
  }
  __syncthreads();
  const int key = koff + tx;
  const int g = (key >> 2) & 3, rr = key & 3, half = (key >> 5) & 1, s1 = (key >> 4) & 1;
  const size_t base = (size_t)bh*S_*D_ + (size_t)kt*8192 + g*16 + half*8 + s1*4 + rr;
#pragma unroll
  for (int r = 0; r < 4; r++) {
    const int d = d0 + ty + r*8;
    VT3[base + d*64] = (_Float16)tile[tx][ty + r*8];
  }
}

// Flash attention, causal (R1 structure: LDS-staged K/V via global_load_lds,
// 32-key double-buffered tiles shared by all 4 waves).
__global__ __launch_bounds__(256, 2)
void attn_fwd(const __hip_bfloat16* __restrict__ Qh,
              const __hip_bfloat16* __restrict__ Kh,
              const _Float16* __restrict__ VT3,
              __hip_bfloat16* __restrict__ O)
{
  __shared__ union {
    struct { unsigned short Kt[2][4096]; _Float16 Vt[2][4096]; } st;
    float ep[64*132];
  } sh;

  const int lane = threadIdx.x & 63;
  const int w    = threadIdx.x >> 6;
  const int L  = blockIdx.x;                   // 0..1023
  const int bh = (L & 7) + 8*((L >> 3) & 3);   // bh pinned to XCD = bh&7
  const int x  = 31 - (L >> 5);                // longest-first
  const int b = bh >> 4, h = bh & 15;
  const int q0 = x*64 + w*16;
  const int qc = lane & 15;
  const int g  = lane >> 4;
  const int qv = q0 + qc;

  const __hip_bfloat16* Kb = Kh + (size_t)bh*S_*D_;
  const _Float16* vtb = VT3 + (size_t)bh*S_*D_;

  const int kswz  = (qc & 7) << 4;                     // K read swizzle (bytes)
  const int vbase = qc*64 + ((g ^ ((qc >> 1) & 3)) << 4);  // V read base (bytes)

#define STAGE(BUF, P) do {                                                       \
    const int kb0_ = (P)*32;                                                     \
    _Pragma("unroll")                                                            \
    for (int ii = 0; ii < 2; ii++) {                                             \
      const int chunk = w*2 + ii;                                                \
      const int key   = chunk*4 + (lane >> 4);                                   \
      const int srcin = ((lane & 15)*16) ^ ((key & 7) << 4);                     \
      async_load16((const char*)Kb + (size_t)(kb0_ + key)*256 + srcin,           \
                   (char*)sh.st.Kt[BUF] + chunk*1024);                           \
    }                                                                            \
    const int kt_ = (P) >> 1, h_ = (P) & 1;                                      \
    _Pragma("unroll")                                                            \
    for (int ii = 0; ii < 2; ii++) {                                             \
      const int chunk = w*2 + ii;                                                \
      const int dd = chunk*16 + (lane >> 2);                                     \
      const int gg = (lane & 3) ^ ((lane >> 3) & 3);                             \
      async_load16((const char*)vtb + ((size_t)kt_*8192 + dd*64 + gg*16 + h_*8)*2,\
                   (char*)sh.st.Vt[BUF] + chunk*1024);                           \
    }                                                                            \
  } while (0)

#define COMPUTE(BUF, P) do {                                                     \
    const int k0_ = (P)*32;                                                      \
    const char* Kl = (const char*)sh.st.Kt[BUF];                                 \
    const char* Vl = (const char*)sh.st.Vt[BUF];                                 \
    bf16x8 ka[4], kbb[4]; f16x8 vv[8];                                           \
    _Pragma("unroll")                                                            \
    for (int c = 0; c < 4; c++) {                                                \
      const int off = (c*64 + g*16) ^ kswz;                                      \
      ka[c]  = *(const bf16x8*)(Kl + qc*256 + off);                              \
      kbb[c] = *(const bf16x8*)(Kl + (16 + qc)*256 + off);                       \
    }                                                                            \
    _Pragma("unroll")                                                            \
    for (int t = 0; t < 8; t++) vv[t] = *(const f16x8*)(Vl + t*1024 + vbase);    \
    f32x4 sA = (f32x4)0.0f, sB = (f32x4)0.0f;                                    \
    _Pragma("unroll")                                                            \
    for (int c = 0; c < 4; c++) {                                                \
      sA = __builtin_amdgcn_mfma_f32_16x16x32_bf16(ka[c],  qf[c], sA, 0, 0, 0);  \
      sB = __builtin_amdgcn_mfma_f32_16x16x32_bf16(kbb[c], qf[c], sB, 0, 0, 0);  \
    }                                                                            \
    float sv[8];                                                                 \
    _Pragma("unroll")                                                            \
    for (int r = 0; r < 4; r++) {                                                \
      sv[r]   = (k0_      + g*4 + r <= qv) ? sA[r]*scale : -1e30f;               \
      sv[4+r] = (k0_ + 16 + g*4 + r <= qv) ? sB[r]*scale : -1e30f;               \
    }                                                                            \
    float mx = sv[0];                                                            \
    _Pragma("unroll")                                                            \
    for (int j = 1; j < 8; j++) mx = fmaxf(mx, sv[j]);                           \
    mx = fmaxf(mx, __shfl_xor(mx, 16));                                          \
    mx = fmaxf(mx, __shfl_xor(mx, 32));                                          \
    const float m_new = fmaxf(m_i, mx);                                          \
    const float alpha = __expf(m_i - m_new);                                     \
    float p[8], ps = 0.0f;                                                       \
    _Pragma("unroll")                                                            \
    for (int j = 0; j < 8; j++) { p[j] = __expf(sv[j] - m_new); ps += p[j]; }    \
    ps += __shfl_xor(ps, 16);                                                    \
    ps += __shfl_xor(ps, 32);                                                    \
    l_i = l_i*alpha + ps;                                                        \
    m_i = m_new;                                                                 \
    f16x4 pA, pB;                                                                \
    _Pragma("unroll")                                                            \
    for (int r = 0; r < 4; r++) { pA[r] = (_Float16)p[r]; pB[r] = (_Float16)p[4+r]; } \
    _Pragma("unroll")                                                            \
    for (int t = 0; t < 8; t++) acc_o[t] *= alpha;                               \
    _Pragma("unroll")                                                            \
    for (int t = 0; t < 8; t++) {                                                \
      const f16x4 vA = __builtin_shufflevector(vv[t], vv[t], 0, 1, 2, 3);        \
      const f16x4 vB = __builtin_shufflevector(vv[t], vv[t], 4, 5, 6, 7);        \
      acc_o[t] = __builtin_amdgcn_mfma_f32_16x16x16f16(vA, pA, acc_o[t], 0, 0, 0); \
      acc_o[t] = __builtin_amdgcn_mfma_f32_16x16x16f16(vB, pB, acc_o[t], 0, 0, 0); \
    }                                                                            \
  } while (0)

  // issue tile-0 DMA first so it flies under the Q register loads
  STAGE(0, 0);

  bf16x8 qf[4];
  {
    const __hip_bfloat16* qrow = Qh + ((size_t)bh*S_ + qv)*D_ + g*8;
#pragma unroll
    for (int c = 0; c < 4; c++) qf[c] = *(const bf16x8*)(qrow + c*32);
  }

  f32x4 acc_o[8];
#pragma unroll
  for (int t = 0; t < 8; t++) acc_o[t] = (f32x4)0.0f;
  float m_i = -1e30f, l_i = 0.0f;
  const float scale = 0.08838834764831845f;   // 1/sqrt(128)

  const int ntile = 2*x + 2;       // 32-key tiles, uniform across the block

  __syncthreads();                 // drains vmcnt(0): tile 0 resident

  for (int p = 0; p < ntile; ++p) {
    if (p + 1 < ntile) STAGE((p + 1) & 1, p + 1);   // async prefetch
    COMPUTE(p & 1, p);
    __syncthreads();               // drain: tile p+1 resident, buf p free
  }

  // epilogue: O^T[d][q] -> LDS as O[q][d] (stride 132), coalesced bf16 store.
  const float inv_l = 1.0f / l_i;
#pragma unroll
  for (int t = 0; t < 8; t++)
#pragma unroll
    for (int r = 0; r < 4; r++)
      sh.ep[(w*16 + qc)*132 + t*16 + g*4 + r] = acc_o[t][r] * inv_l;
  __syncthreads();

  const int row = threadIdx.x >> 2;          // 0..63
  const int c0  = (threadIdx.x & 3) * 32;
  unsigned short* Os = (unsigned short*)O;
  const size_t obase = ((size_t)b*S_ + x*64 + row)*E_ + h*D_;
#pragma unroll
  for (int i = 0; i < 8; i++) {
    const f32x4 v4 = *(const f32x4*)(sh.ep + row*132 + c0 + i*4);
    u16x4 o4;
    o4.x = f2bf(v4.x); o4.y = f2bf(v4.y); o4.z = f2bf(v4.z); o4.w = f2bf(v4.w);
    *(u16x4*)(Os + obase + c0 + i*4) = o4;
  }
#undef STAGE
#undef COMPUTE
}

extern "C" void kernel_launch(void* const* d_in, const int* in_sizes, int n_in,
                              void* d_out, int out_size, void* d_ws, size_t ws_size,
                              hipStream_t stream)
{
  (void)in_sizes; (void)n_in; (void)out_size; (void)ws_size;
  const float* act = (const float*)d_in[0];
  const float* Wq  = (const float*)d_in[1];
  const float* Wk  = (const float*)d_in[2];
  const float* Wv  = (const float*)d_in[3];
  const float* Wo  = (const float*)d_in[4];

  __hip_bfloat16* actb = (__hip_bfloat16*)d_ws;
  __hip_bfloat16* Wqb  = actb + ELEMS;
  __hip_bfloat16* Wkb  = Wqb + WELEMS;
  __hip_bfloat16* Wvb  = Wkb + WELEMS;
  __hip_bfloat16* Wob  = Wvb + WELEMS;
  __hip_bfloat16* Q    = Wob + WELEMS;
  __hip_bfloat16* Kp   = Q + ELEMS;
  __hip_bfloat16* V    = Kp + ELEMS;
  _Float16*       VT   = (_Float16*)(V + ELEMS);
  __hip_bfloat16* AO   = V;   // V dead after transpose_v; reuse for attn output

  cvt_f32_bf16<<<ELEMS/4/256, 256, 0, stream>>>(act, (unsigned short*)actb, ELEMS/4);
  cvt4_f32_bf16<<<dim3(WELEMS/4/256, 4), 256, 0, stream>>>(
      Wq, Wk, Wv, Wo,
      (unsigned short*)Wqb, (unsigned short*)Wkb,
      (unsigned short*)Wvb, (unsigned short*)Wob, WELEMS/4);

  // Fused QKV projection: [4096 x 6144 x 2048] on the ring-3 kernel;
  // grid = 16*48 = 768 = 3 exact rounds of 256 CUs; 144 KiB dynamic LDS.
  gemm_ring3<3><<<(B_*S_/256)*(3*E_/128), 512, 147456, stream>>>(
      actb, Wqb, Q, B_*S_, 3*E_, E_);

  xpos_rotary<<<(B_*S_*H_*64)/256, 256, 0, stream>>>(Q, Kp);
  transpose_v<<<dim3(S_/32, D_/32, B_*H_), dim3(32, 8), 0, stream>>>(V, VT);
  attn_fwd<<<1024, 256, 0, stream>>>(Q, Kp, VT, AO);

  // Wo projection: [4096 x 2048 x 2048], grid 16*16 = 256 = 1 exact round.
  gemm_ring3<1><<<(B_*S_/256)*(E_/128), 512, 147456, stream>>>(
      AO, Wob, d_out, B_*S_, E_, E_);
}

// Round 8
// 373.206 us; speedup vs baseline: 1.0788x; 1.0788x over previous
//
#include <hip/hip_runtime.h>
#include <hip/hip_bf16.h>

typedef __attribute__((ext_vector_type(8))) short bf16x8;
typedef __attribute__((ext_vector_type(4))) float f32x4;
typedef __attribute__((ext_vector_type(4))) _Float16 f16x4;
typedef __attribute__((ext_vector_type(8))) _Float16 f16x8;
typedef __attribute__((ext_vector_type(4))) unsigned short u16x4;

#define B_ 2
#define S_ 2048
#define E_ 2048
#define H_ 16
#define D_ 128
#define ELEMS (B_*S_*E_)   // 8388608 elements of [B,S,2048]
#define WELEMS (E_*E_)     // 4194304 elements per weight matrix

__device__ __forceinline__ unsigned short f2bf(float x) {
  unsigned int u = __float_as_uint(x);
  u += 0x7fffu + ((u >> 16) & 1u);
  return (unsigned short)(u >> 16);
}

__device__ __forceinline__ void async_load16(const void* g, void* l) {
  __builtin_amdgcn_global_load_lds(
      (const __attribute__((address_space(1))) unsigned int*)g,
      (__attribute__((address_space(3))) unsigned int*)l, 16, 0, 0);
}

// f32 -> bf16 (RNE), vectorized x4. n4 = n/4.
__global__ __launch_bounds__(256)
void cvt_f32_bf16(const float* __restrict__ src, unsigned short* __restrict__ dst, int n4)
{
  const int i = blockIdx.x * 256 + threadIdx.x;
  if (i < n4) {
    const f32x4 v = ((const f32x4*)src)[i];
    u16x4 o;
    o.x = f2bf(v.x); o.y = f2bf(v.y); o.z = f2bf(v.z); o.w = f2bf(v.w);
    ((u16x4*)dst)[i] = o;
  }
}

// four equally-sized weight tensors in one launch (blockIdx.y selects)
__global__ __launch_bounds__(256)
void cvt4_f32_bf16(const float* __restrict__ s0, const float* __restrict__ s1,
                   const float* __restrict__ s2, const float* __restrict__ s3,
                   unsigned short* __restrict__ d0, unsigned short* __restrict__ d1,
                   unsigned short* __restrict__ d2, unsigned short* __restrict__ d3,
                   int n4)
{
  const int i = blockIdx.x * 256 + threadIdx.x;
  if (i >= n4) return;
  const float* s; unsigned short* d;
  switch (blockIdx.y) {
    case 0: s = s0; d = d0; break;
    case 1: s = s1; d = d1; break;
    case 2: s = s2; d = d2; break;
    default: s = s3; d = d3; break;
  }
  const f32x4 v = ((const f32x4*)s)[i];
  u16x4 o;
  o.x = f2bf(v.x); o.y = f2bf(v.y); o.z = f2bf(v.z); o.w = f2bf(v.w);
  ((u16x4*)d)[i] = o;
}

// ---------------------------------------------------------------------------
// 256x128-tile GEMM, ring-3 LDS, single barrier per K-tile (R7).
// R6 (NaN) autopsy: raw s_barrier is IntrNoMem -> the scheduler may hoist the
// next tile's ds_reads above it (R6's x3-unrolled ring made them straight-line
// const-addressed code), reading LDS chunks other waves' DMAs hadn't landed.
// R7 fixes: (a) sched_barrier(0) immediately after EVERY s_barrier (fences
// both directions); (b) staging addresses reverted to the R5-proven explicit
// form (builtin offset arg = 0 always); (c) no inline lgkmcnt at all - all 16
// ds_reads + both MFMA clusters live in one region and the compiler inserts
// its own fine-grained lgkmcnt(N) (measured near-optimal), giving the
// intended MFMA(kk0) || ds_read(kk1) overlap without fragile manual counts.
// Ring-3 (144 KiB), staging 2 K-tiles ahead, counted VMW(6) - never 0 in
// the steady loop. Swizzle (verified 0 conflicts): 16B-slot ^= (row>>1)&3,
// both-sides. Grids: QKV 768 = 3 exact rounds, Wo 256 = 1 exact round.
template<int OUTMODE>
__global__ __launch_bounds__(512, 2)
void gemm_p4(const __hip_bfloat16* __restrict__ A,
             const __hip_bfloat16* __restrict__ Bw,
             void* __restrict__ C, int M, int N, int K)
{
  extern __shared__ char lds[];
  const int lane = threadIdx.x & 63;
  const int w    = threadIdx.x >> 6;   // 0..7
  const int fr   = lane & 15;
  const int fg   = lane >> 4;          // 0..3

  // XCD-aware swizzle of the linear block id (grid % 8 == 0)
  const int nblk = N >> 7;             // N / 128
  const int cpx  = gridDim.x >> 3;
  const int lin  = blockIdx.x;
  const int swz  = (lin & 7) * cpx + (lin >> 3);
  const int m0 = (swz / nblk) << 8;
  const int n0 = (swz % nblk) << 7;

  // LDS geometry (per 48-KB buffer): A at 0 (kk*16384), B at 32768 (kk*8192);
  // row stride 64 B; 16B-slot ^= (row>>1)&3.
  const int Ssw = (fg ^ ((fr >> 1) & 3)) << 4;
  const int pA  = ((w >> 1) * 64 + fr) * 64 + Ssw;          // + mi*1024 + kk*16384
  const int pB  = 32768 + ((w & 1) * 64 + fr) * 64 + Ssw;   // + nj*1024 + kk*8192

  // Staging: 6 DMAs per tile (A rows 0-127, A rows 128-255, B rows 0-127,
  // each x 2 kk-halves). Dest slot linear in lane (valid for global_load_lds);
  // source k-group pre-swizzled (lane&3)^((lane>>3)&3). kk1 source = +32
  // elements (explicit pointer arithmetic, builtin offset stays 0 - the
  // R5-verified path). Pointers advance +64 elems (one K-tile) per tile.
  const int srow = w * 16 + (lane >> 2);               // 0..127
  const int ks   = ((lane & 3) ^ ((lane >> 3) & 3)) * 8;
  const __hip_bfloat16* Asrc  = A  + (size_t)(m0 + srow) * K + ks;
  const __hip_bfloat16* A2src = Asrc + (size_t)128 * K;
  const __hip_bfloat16* Bsrc  = Bw + (size_t)(n0 + srow) * K + ks;
  const int dstA = srow * 64 + (lane & 3) * 16;        // < 8192

#define STG(NB) do {                                                           \
    async_load16(Asrc,       lds + (NB)*49152 +                 dstA);         \
    async_load16(Asrc + 32,  lds + (NB)*49152 + 16384 +         dstA);         \
    async_load16(A2src,      lds + (NB)*49152 +          8192 + dstA);         \
    async_load16(A2src + 32, lds + (NB)*49152 + 16384 +  8192 + dstA);         \
    async_load16(Bsrc,       lds + (NB)*49152 + 32768 +         dstA);         \
    async_load16(Bsrc + 32,  lds + (NB)*49152 + 32768 +  8192 + dstA);         \
  } while (0)

#define ADV() do { Asrc += 64; A2src += 64; Bsrc += 64; } while (0)

#define RD(AR, BR, KK, BB) do {                                                \
    const char* pa_ = lds + (BB)*49152 + (KK)*16384 + pA;                      \
    AR[0] = *(const bf16x8*)(pa_);        AR[1] = *(const bf16x8*)(pa_ + 1024);\
    AR[2] = *(const bf16x8*)(pa_ + 2048); AR[3] = *(const bf16x8*)(pa_ + 3072);\
    const char* pb_ = lds + (BB)*49152 + (KK)*8192 + pB;                       \
    BR[0] = *(const bf16x8*)(pb_);        BR[1] = *(const bf16x8*)(pb_ + 1024);\
    BR[2] = *(const bf16x8*)(pb_ + 2048); BR[3] = *(const bf16x8*)(pb_ + 3072);\
  } while (0)

#define MFMA16(AR, BR)                                                         \
    _Pragma("unroll")                                                          \
    for (int i_ = 0; i_ < 4; i_++)                                             \
    _Pragma("unroll")                                                          \
    for (int j_ = 0; j_ < 4; j_++)                                             \
      acc[i_][j_] = __builtin_amdgcn_mfma_f32_16x16x32_bf16(                   \
          AR[i_], BR[j_], acc[i_][j_], 0, 0, 0)

#define SB0()  __builtin_amdgcn_sched_barrier(0)
#define BARX() do { __builtin_amdgcn_s_barrier(); SB0(); } while (0)
#define VMW(NN) asm volatile("s_waitcnt vmcnt(" #NN ")" ::: "memory")
#define PRIO(P) __builtin_amdgcn_s_setprio(P)

// One K-tile: issue all 16 ds_reads + 6 staging DMAs, then both MFMA
// clusters; the compiler schedules loads vs MFMAs with its own fine-grained
// lgkmcnt. Counted vmcnt keeps 6 DMAs (tile t+2) in flight across the
// barrier; BARX's trailing sched_barrier stops cross-tile hoisting.
#define TILE(BB, NB, T) do {                                                   \
    const bool stg_ = (T) + 2 < nk;                                            \
    RD(a0, b0, 0, BB);                                                         \
    RD(a1, b1, 1, BB);                                                         \
    if (stg_) { STG(NB); ADV(); }                                              \
    PRIO(1); MFMA16(a0, b0); MFMA16(a1, b1); PRIO(0);                          \
    if (stg_) { VMW(6); } else { VMW(0); }                                     \
    BARX();                                                                    \
  } while (0)

  f32x4 acc[4][4];
#pragma unroll
  for (int i = 0; i < 4; i++)
#pragma unroll
    for (int j = 0; j < 4; j++) acc[i][j] = (f32x4)0.0f;

  bf16x8 a0[4], b0[4], a1[4], b1[4];

  const int nk = K >> 6;   // K-tiles of 64

  // prologue: stage tile 0 -> buf0, tile 1 -> buf1; pointers end at tile 2
  STG(0); ADV();
  STG(1); ADV();
  VMW(6);          // tile 0's 6 landed; tile 1's 6 still in flight
  BARX();

  int t = 0;
  for (; t + 3 <= nk; t += 3) {
    TILE(0, 2, t);
    TILE(1, 0, t + 1);
    TILE(2, 1, t + 2);
  }
  if (t < nk) { TILE(0, 2, t); ++t; }
  if (t < nk) { TILE(1, 0, t); ++t; }

  // epilogue: direct scattered C write (same fragment->C map as before)
  const int wr = (w >> 1) * 64, wc = (w & 1) * 64;
#pragma unroll
  for (int mi = 0; mi < 4; mi++) {
    const int row = m0 + wr + mi*16 + fg*4;
#pragma unroll
    for (int nj = 0; nj < 4; nj++) {
      const int col = n0 + wc + nj*16 + fr;
#pragma unroll
      for (int r = 0; r < 4; r++) {
        if (OUTMODE == 1) {
          ((float*)C)[(size_t)(row + r)*N + col] = acc[mi][nj][r];
        } else if (OUTMODE == 0) {
          ((unsigned short*)C)[(size_t)(row + r)*N + col] = f2bf(acc[mi][nj][r]);
        } else if (OUTMODE == 2) {
          const int rr = row + r;
          const int b = rr >> 11, s = rr & 2047;
          const int h = col >> 7, d = col & 127;
          ((unsigned short*)C)[(((size_t)(b*H_ + h) << 11) + s)*D_ + d] = f2bf(acc[mi][nj][r]);
        } else {   // OUTMODE == 3: fused QKV, outputs contiguous ELEMS apart
          const int rr = row + r;
          const int b = rr >> 11, s = rr & 2047;
          const int t2 = col >> 11;            // 0=Q 1=K 2=V
          const int h = (col >> 7) & 15, d = col & 127;
          ((unsigned short*)C)[(size_t)t2*ELEMS +
              (((size_t)(b*H_ + h) << 11) + s)*D_ + d] = f2bf(acc[mi][nj][r]);
        }
      }
    }
  }
#undef STG
#undef ADV
#undef RD
#undef MFMA16
#undef SB0
#undef BARX
#undef VMW
#undef PRIO
#undef TILE
}

// xpos rotary, in place on head-major bf16 Q and K [b,h,s,d].
__global__ __launch_bounds__(256)
void xpos_rotary(__hip_bfloat16* __restrict__ Q, __hip_bfloat16* __restrict__ Kt)
{
  const int idx = blockIdx.x * 256 + threadIdx.x;   // [0, B*H*S*64)
  const int j = idx & 63;
  const int s = (idx >> 6) & 2047;
  const float seq = (float)(s - 1024) * (1.0f/512.0f);
  const float dr = 2.0f + 2.0f*(float)j;
  const float theta = expf(dr * (1.0f/128.0f) * -9.210340371976184f);
  const float zeta  = (dr * (1.0f/64.0f) + 51.2f) * (1.0f/52.2f);
  const float ang = seq * theta;
  const float c  = cosf(ang);
  const float sn = sinf(ang);
  const float t  = expf(seq * logf(zeta));
  const float it = 1.0f / t;

  const size_t base = (size_t)(idx >> 6) * 128 + 2*j;
  unsigned short* Qs = (unsigned short*)Q;
  unsigned short* Ks = (unsigned short*)Kt;
  const float q0 = __bfloat162float(Q[base]),  q1 = __bfloat162float(Q[base+1]);
  Qs[base]   = f2bf((q0*c - q1*sn) * t);
  Qs[base+1] = f2bf((q1*c + q0*sn) * t);
  const float k0 = __bfloat162float(Kt[base]), k1 = __bfloat162float(Kt[base+1]);
  Ks[base]   = f2bf((k0*c - k1*sn) * it);
  Ks[base+1] = f2bf((k1*c + k0*sn) * it);
}

// Vh [b,h,s,d] bf16 -> VT3 packed f16:
// per (bh, kt=s/64) 16-KB tile, inner offset = d*64 + g*16 + half*8 + s1*4 + r
// where key=s%64 = (half*2+s1)*16 + g*4 + r.
__global__ __launch_bounds__(256)
void transpose_v(const __hip_bfloat16* __restrict__ Vh, _Float16* __restrict__ VT3)
{
  __shared__ float tile[32][33];
  const int tx = threadIdx.x, ty = threadIdx.y;      // block (32, 8)
  const int bh = blockIdx.z;
  const int s0 = blockIdx.x * 32, d0 = blockIdx.y * 32;
  const int kt = s0 >> 6, koff = s0 & 63;
#pragma unroll
  for (int r = 0; r < 4; r++) {
    const int s = s0 + ty + r*8;
    tile[ty + r*8][tx] = __bfloat162float(Vh[((size_t)bh*S_ + s)*D_ + d0 + tx]);
  }
  __syncthreads();
  const int key = koff + tx;
  const int g = (key >> 2) & 3, rr = key & 3, half = (key >> 5) & 1, s1 = (key >> 4) & 1;
  const size_t base = (size_t)bh*S_*D_ + (size_t)kt*8192 + g*16 + half*8 + s1*4 + rr;
#pragma unroll
  for (int r = 0; r < 4; r++) {
    const int d = d0 + ty + r*8;
    VT3[base + d*64] = (_Float16)tile[tx][ty + r*8];
  }
}

// Flash attention, causal (R1 structure: LDS-staged K/V via global_load_lds,
// 32-key double-buffered tiles shared by all 4 waves).
__global__ __launch_bounds__(256, 2)
void attn_fwd(const __hip_bfloat16* __restrict__ Qh,
              const __hip_bfloat16* __restrict__ Kh,
              const _Float16* __restrict__ VT3,
              __hip_bfloat16* __restrict__ O)
{
  __shared__ union {
    struct { unsigned short Kt[2][4096]; _Float16 Vt[2][4096]; } st;
    float ep[64*132];
  } sh;

  const int lane = threadIdx.x & 63;
  const int w    = threadIdx.x >> 6;
  const int L  = blockIdx.x;                   // 0..1023
  const int bh = (L & 7) + 8*((L >> 3) & 3);   // bh pinned to XCD = bh&7
  const int x  = 31 - (L >> 5);                // longest-first
  const int b = bh >> 4, h = bh & 15;
  const int q0 = x*64 + w*16;
  const int qc = lane & 15;
  const int g  = lane >> 4;
  const int qv = q0 + qc;

  const __hip_bfloat16* Kb = Kh + (size_t)bh*S_*D_;
  const _Float16* vtb = VT3 + (size_t)bh*S_*D_;

  const int kswz  = (qc & 7) << 4;                     // K read swizzle (bytes)
  const int vbase = qc*64 + ((g ^ ((qc >> 1) & 3)) << 4);  // V read base (bytes)

#define STAGE(BUF, P) do {                                                       \
    const int kb0_ = (P)*32;                                                     \
    _Pragma("unroll")                                                            \
    for (int ii = 0; ii < 2; ii++) {                                             \
      const int chunk = w*2 + ii;                                                \
      const int key   = chunk*4 + (lane >> 4);                                   \
      const int srcin = ((lane & 15)*16) ^ ((key & 7) << 4);                     \
      async_load16((const char*)Kb + (size_t)(kb0_ + key)*256 + srcin,           \
                   (char*)sh.st.Kt[BUF] + chunk*1024);                           \
    }                                                                            \
    const int kt_ = (P) >> 1, h_ = (P) & 1;                                      \
    _Pragma("unroll")                                                            \
    for (int ii = 0; ii < 2; ii++) {                                             \
      const int chunk = w*2 + ii;                                                \
      const int dd = chunk*16 + (lane >> 2);                                     \
      const int gg = (lane & 3) ^ ((lane >> 3) & 3);                             \
      async_load16((const char*)vtb + ((size_t)kt_*8192 + dd*64 + gg*16 + h_*8)*2,\
                   (char*)sh.st.Vt[BUF] + chunk*1024);                           \
    }                                                                            \
  } while (0)

#define COMPUTE(BUF, P) do {                                                     \
    const int k0_ = (P)*32;                                                      \
    const char* Kl = (const char*)sh.st.Kt[BUF];                                 \
    const char* Vl = (const char*)sh.st.Vt[BUF];                                 \
    bf16x8 ka[4], kbb[4]; f16x8 vv[8];                                           \
    _Pragma("unroll")                                                            \
    for (int c = 0; c < 4; c++) {                                                \
      const int off = (c*64 + g*16) ^ kswz;                                      \
      ka[c]  = *(const bf16x8*)(Kl + qc*256 + off);                              \
      kbb[c] = *(const bf16x8*)(Kl + (16 + qc)*256 + off);                       \
    }                                                                            \
    _Pragma("unroll")                                                            \
    for (int t = 0; t < 8; t++) vv[t] = *(const f16x8*)(Vl + t*1024 + vbase);    \
    f32x4 sA = (f32x4)0.0f, sB = (f32x4)0.0f;                                    \
    _Pragma("unroll")                                                            \
    for (int c = 0; c < 4; c++) {                                                \
      sA = __builtin_amdgcn_mfma_f32_16x16x32_bf16(ka[c],  qf[c], sA, 0, 0, 0);  \
      sB = __builtin_amdgcn_mfma_f32_16x16x32_bf16(kbb[c], qf[c], sB, 0, 0, 0);  \
    }                                                                            \
    float sv[8];                                                                 \
    _Pragma("unroll")                                                            \
    for (int r = 0; r < 4; r++) {                                                \
      sv[r]   = (k0_      + g*4 + r <= qv) ? sA[r]*scale : -1e30f;               \
      sv[4+r] = (k0_ + 16 + g*4 + r <= qv) ? sB[r]*scale : -1e30f;               \
    }                                                                            \
    float mx = sv[0];                                                            \
    _Pragma("unroll")                                                            \
    for (int j = 1; j < 8; j++) mx = fmaxf(mx, sv[j]);                           \
    mx = fmaxf(mx, __shfl_xor(mx, 16));                                          \
    mx = fmaxf(mx, __shfl_xor(mx, 32));                                          \
    const float m_new = fmaxf(m_i, mx);                                          \
    const float alpha = __expf(m_i - m_new);                                     \
    float p[8], ps = 0.0f;                                                       \
    _Pragma("unroll")                                                            \
    for (int j = 0; j < 8; j++) { p[j] = __expf(sv[j] - m_new); ps += p[j]; }    \
    ps += __shfl_xor(ps, 16);                                                    \
    ps += __shfl_xor(ps, 32);                                                    \
    l_i = l_i*alpha + ps;                                                        \
    m_i = m_new;                                                                 \
    f16x4 pA, pB;                                                                \
    _Pragma("unroll")                                                            \
    for (int r = 0; r < 4; r++) { pA[r] = (_Float16)p[r]; pB[r] = (_Float16)p[4+r]; } \
    _Pragma("unroll")                                                            \
    for (int t = 0; t < 8; t++) acc_o[t] *= alpha;                               \
    _Pragma("unroll")                                                            \
    for (int t = 0; t < 8; t++) {                                                \
      const f16x4 vA = __builtin_shufflevector(vv[t], vv[t], 0, 1, 2, 3);        \
      const f16x4 vB = __builtin_shufflevector(vv[t], vv[t], 4, 5, 6, 7);        \
      acc_o[t] = __builtin_amdgcn_mfma_f32_16x16x16f16(vA, pA, acc_o[t], 0, 0, 0); \
      acc_o[t] = __builtin_amdgcn_mfma_f32_16x16x16f16(vB, pB, acc_o[t], 0, 0, 0); \
    }                                                                            \
  } while (0)

  // issue tile-0 DMA first so it flies under the Q register loads
  STAGE(0, 0);

  bf16x8 qf[4];
  {
    const __hip_bfloat16* qrow = Qh + ((size_t)bh*S_ + qv)*D_ + g*8;
#pragma unroll
    for (int c = 0; c < 4; c++) qf[c] = *(const bf16x8*)(qrow + c*32);
  }

  f32x4 acc_o[8];
#pragma unroll
  for (int t = 0; t < 8; t++) acc_o[t] = (f32x4)0.0f;
  float m_i = -1e30f, l_i = 0.0f;
  const float scale = 0.08838834764831845f;   // 1/sqrt(128)

  const int ntile = 2*x + 2;       // 32-key tiles, uniform across the block

  __syncthreads();                 // drains vmcnt(0): tile 0 resident

  for (int p = 0; p < ntile; ++p) {
    if (p + 1 < ntile) STAGE((p + 1) & 1, p + 1);   // async prefetch
    COMPUTE(p & 1, p);
    __syncthreads();               // drain: tile p+1 resident, buf p free
  }

  // epilogue: O^T[d][q] -> LDS as O[q][d] (stride 132), coalesced bf16 store.
  const float inv_l = 1.0f / l_i;
#pragma unroll
  for (int t = 0; t < 8; t++)
#pragma unroll
    for (int r = 0; r < 4; r++)
      sh.ep[(w*16 + qc)*132 + t*16 + g*4 + r] = acc_o[t][r] * inv_l;
  __syncthreads();

  const int row = threadIdx.x >> 2;          // 0..63
  const int c0  = (threadIdx.x & 3) * 32;
  unsigned short* Os = (unsigned short*)O;
  const size_t obase = ((size_t)b*S_ + x*64 + row)*E_ + h*D_;
#pragma unroll
  for (int i = 0; i < 8; i++) {
    const f32x4 v4 = *(const f32x4*)(sh.ep + row*132 + c0 + i*4);
    u16x4 o4;
    o4.x = f2bf(v4.x); o4.y = f2bf(v4.y); o4.z = f2bf(v4.z); o4.w = f2bf(v4.w);
    *(u16x4*)(Os + obase + c0 + i*4) = o4;
  }
#undef STAGE
#undef COMPUTE
}

extern "C" void kernel_launch(void* const* d_in, const int* in_sizes, int n_in,
                              void* d_out, int out_size, void* d_ws, size_t ws_size,
                              hipStream_t stream)
{
  (void)in_sizes; (void)n_in; (void)out_size; (void)ws_size;
  const float* act = (const float*)d_in[0];
  const float* Wq  = (const float*)d_in[1];
  const float* Wk  = (const float*)d_in[2];
  const float* Wv  = (const float*)d_in[3];
  const float* Wo  = (const float*)d_in[4];

  __hip_bfloat16* actb = (__hip_bfloat16*)d_ws;
  __hip_bfloat16* Wqb  = actb + ELEMS;
  __hip_bfloat16* Wkb  = Wqb + WELEMS;
  __hip_bfloat16* Wvb  = Wkb + WELEMS;
  __hip_bfloat16* Wob  = Wvb + WELEMS;
  __hip_bfloat16* Q    = Wob + WELEMS;
  __hip_bfloat16* Kp   = Q + ELEMS;
  __hip_bfloat16* V    = Kp + ELEMS;
  _Float16*       VT   = (_Float16*)(V + ELEMS);
  __hip_bfloat16* AO   = V;   // V dead after transpose_v; reuse for attn output

  cvt_f32_bf16<<<ELEMS/4/256, 256, 0, stream>>>(act, (unsigned short*)actb, ELEMS/4);
  cvt4_f32_bf16<<<dim3(WELEMS/4/256, 4), 256, 0, stream>>>(
      Wq, Wk, Wv, Wo,
      (unsigned short*)Wqb, (unsigned short*)Wkb,
      (unsigned short*)Wvb, (unsigned short*)Wob, WELEMS/4);

  // Fused QKV projection: [4096 x 6144 x 2048] on the ring-3 kernel;
  // grid = 16*48 = 768 = 3 exact rounds of 256 CUs; 144 KiB dynamic LDS.
  gemm_p4<3><<<(B_*S_/256)*(3*E_/128), 512, 147456, stream>>>(
      actb, Wqb, Q, B_*S_, 3*E_, E_);

  xpos_rotary<<<(B_*S_*H_*64)/256, 256, 0, stream>>>(Q, Kp);
  transpose_v<<<dim3(S_/32, D_/32, B_*H_), dim3(32, 8), 0, stream>>>(V, VT);
  attn_fwd<<<1024, 256, 0, stream>>>(Q, Kp, VT, AO);

  // Wo projection: [4096 x 2048 x 2048], grid 16*16 = 256 = 1 exact round.
  gemm_p4<1><<<(B_*S_/256)*(E_/128), 512, 147456, stream>>>(
      AO, Wob, d_out, B_*S_, E_, E_);
}